// Round 1
// baseline (83.381 us; speedup 1.0000x reference)
//
#include <hip/hip_runtime.h>
#include <hip/hip_bf16.h>

#define BB 4
#define TT 2048
#define CC 1024
#define HH 64

typedef __attribute__((ext_vector_type(8))) unsigned short ushort8;
typedef __attribute__((ext_vector_type(4))) unsigned short ushort4v;
typedef __attribute__((ext_vector_type(8))) __bf16 bf16x8;
typedef __attribute__((ext_vector_type(4))) float float4v;

static __device__ __forceinline__ unsigned short f2bf(float f) {
    // round-to-nearest-even f32 -> bf16
    unsigned int u = __builtin_bit_cast(unsigned int, f);
    u += 0x7fffu + ((u >> 16) & 1u);
    return (unsigned short)(u >> 16);
}

static __device__ __forceinline__ float4v mfma16(ushort8 a, ushort8 b, float4v c) {
    return __builtin_amdgcn_mfma_f32_16x16x32_bf16(
        __builtin_bit_cast(bf16x8, a), __builtin_bit_cast(bf16x8, b), c, 0, 0, 0);
}

// ---------------------------------------------------------------------------
// Kernel 1: projections. q = (x*Wq)/8 (scale folded), k = x*Wk  (row-major
// bf16 [B*T][64]); v = x*Wv stored TRANSPOSED as vT[b][h][t] bf16 so the
// attention PV A-fragment loads are contiguous 8B chunks.
// Block: 256 thr (4 waves), 64 rows, K-loop step 32, MFMA 16x16x32.
// ---------------------------------------------------------------------------
__global__ __launch_bounds__(256) void proj_kernel(
    const float* __restrict__ x,
    const float* __restrict__ Wq, const float* __restrict__ Wk, const float* __restrict__ Wv,
    unsigned short* __restrict__ qo, unsigned short* __restrict__ ko,
    unsigned short* __restrict__ vo)
{
    __shared__ __align__(16) unsigned short xs[64][40];  // 64 rows x 32 k, pad->40
    __shared__ __align__(16) unsigned short wt[64][40];  // W^T: 64 n x 32 k, pad->40

    const int y = blockIdx.y;                       // 0=q, 1=k, 2=v
    const float* __restrict__ W = (y == 0) ? Wq : (y == 1) ? Wk : Wv;
    const int row0 = blockIdx.x * 64;
    const int tid = threadIdx.x;
    const int lane = tid & 63;
    const int wv = tid >> 6;
    const int l15 = lane & 15;
    const int g = lane >> 4;

    const int xr = tid >> 2;            // 0..63 row for x staging
    const int xk = (tid & 3) << 3;      // 0,8,16,24
    const int wn = tid & 63;            // 0..63 col of W
    const int wks = (tid >> 6) << 3;    // 0,8,16,24 k-slice

    float4v acc[4];
#pragma unroll
    for (int i = 0; i < 4; ++i) acc[i] = (float4v)0.0f;

    for (int k0 = 0; k0 < CC; k0 += 32) {
        {   // stage x tile (64 x 32) -> bf16 LDS
            const float* src = x + (size_t)(row0 + xr) * CC + (k0 + xk);
            float4v a = *(const float4v*)src;
            float4v b = *(const float4v*)(src + 4);
            ushort8 p;
#pragma unroll
            for (int i = 0; i < 4; ++i) { p[i] = f2bf(a[i]); p[4 + i] = f2bf(b[i]); }
            *(ushort8*)&xs[xr][xk] = p;
        }
        {   // stage W^T tile (64 n x 32 k) -> bf16 LDS (coalesced column reads)
            ushort8 p;
#pragma unroll
            for (int i = 0; i < 8; ++i) p[i] = f2bf(W[(size_t)(k0 + wks + i) * HH + wn]);
            *(ushort8*)&wt[wn][wks] = p;
        }
        __syncthreads();
        ushort8 af = *(const ushort8*)&xs[16 * wv + l15][8 * g];
#pragma unroll
        for (int nf = 0; nf < 4; ++nf) {
            ushort8 bfr = *(const ushort8*)&wt[16 * nf + l15][8 * g];
            acc[nf] = mfma16(af, bfr, acc[nf]);
        }
        __syncthreads();
    }

    // C/D layout (m89-verified): col = lane&15, row = 4*(lane>>4) + reg
    const int rbase = row0 + 16 * wv + 4 * g;
    if (y == 0) {
#pragma unroll
        for (int nf = 0; nf < 4; ++nf)
#pragma unroll
            for (int r = 0; r < 4; ++r)
                qo[(size_t)(rbase + r) * HH + 16 * nf + l15] = f2bf(acc[nf][r] * 0.125f);
    } else if (y == 1) {
#pragma unroll
        for (int nf = 0; nf < 4; ++nf)
#pragma unroll
            for (int r = 0; r < 4; ++r)
                ko[(size_t)(rbase + r) * HH + 16 * nf + l15] = f2bf(acc[nf][r]);
    } else {
        const int bidx = rbase >> 11;          // /2048 (64-row blocks never straddle)
        const int t0 = rbase & (TT - 1);
#pragma unroll
        for (int nf = 0; nf < 4; ++nf) {
            ushort4v pv;
#pragma unroll
            for (int r = 0; r < 4; ++r) pv[r] = f2bf(acc[nf][r]);
            *(ushort4v*)&vo[((size_t)bidx * HH + 16 * nf + l15) * TT + t0] = pv;
        }
    }
}

// ---------------------------------------------------------------------------
// Kernel 2: causal flash attention, 1 wave per 16 queries, KVBLK=32.
// Swapped QK^T: S^T = mfma(K, Q^T) -> lane owns one query (col=lane&15),
// keys live in (g,reg). Softmax row-reduce = 2 shfl_xor. PV reuses the S/P
// register layout directly as the B-fragment (custom k-permutation kappa,
// identical on A and B, so any bijection is correct); V^T gathered to match.
// ---------------------------------------------------------------------------
__global__ __launch_bounds__(64) void attn_kernel(
    const unsigned short* __restrict__ qw,
    const unsigned short* __restrict__ kw,
    const unsigned short* __restrict__ vw,
    float* __restrict__ out)
{
    const int idx = blockIdx.x;
    const int b = idx & (BB - 1);
    const int qt = (TT / 16 - 1) - (idx >> 2);  // heavy tiles dispatched first
    const int q0 = qt << 4;
    const int lane = threadIdx.x;
    const int l15 = lane & 15;
    const int g = lane >> 4;
    const int q = q0 + l15;                      // this lane's query row

    const unsigned short* qrow = qw + (size_t)(b * TT + q) * HH + 8 * g;
    ushort8 qf0 = *(const ushort8*)qrow;         // h 0..31 slice (k=8g..8g+7)
    ushort8 qf1 = *(const ushort8*)(qrow + 32);  // h 32..63 slice

    const unsigned short* kb = kw + (size_t)b * TT * HH;
    const unsigned short* vb = vw + (size_t)b * HH * TT;

    float m_run = -3.0e38f, l_run = 0.0f;
    float4v o[4];
#pragma unroll
    for (int i = 0; i < 4; ++i) o[i] = (float4v)0.0f;

    const int ks_end = q0 + 16;
    for (int kv0 = 0; kv0 < ks_end; kv0 += 32) {
        // K A-fragments: rows = keys, k = h
        const unsigned short* kr = kb + (size_t)(kv0 + l15) * HH + 8 * g;
        ushort8 ak00 = *(const ushort8*)kr;
        ushort8 ak01 = *(const ushort8*)(kr + 32);
        ushort8 ak10 = *(const ushort8*)(kr + 16 * HH);
        ushort8 ak11 = *(const ushort8*)(kr + 16 * HH + 32);

        float4v s0 = (float4v)0.0f, s1 = (float4v)0.0f;  // S^T: lane=q, reg=key
        s0 = mfma16(ak00, qf0, s0);
        s0 = mfma16(ak01, qf1, s0);
        s1 = mfma16(ak10, qf0, s1);
        s1 = mfma16(ak11, qf1, s1);

        if (kv0 + 31 > q0) {  // partial tile: causal mask
            const int kbase0 = kv0 + 4 * g;
#pragma unroll
            for (int r = 0; r < 4; ++r) {
                if (kbase0 + r > q) s0[r] = -1e30f;
                if (kbase0 + 16 + r > q) s1[r] = -1e30f;
            }
        }

        // online softmax: reduce over this lane's 8 keys + across g-groups
        float mt = s0[0];
#pragma unroll
        for (int r = 1; r < 4; ++r) mt = fmaxf(mt, s0[r]);
#pragma unroll
        for (int r = 0; r < 4; ++r) mt = fmaxf(mt, s1[r]);
        mt = fmaxf(mt, __shfl_xor(mt, 16, 64));
        mt = fmaxf(mt, __shfl_xor(mt, 32, 64));

        const float m_new = fmaxf(m_run, mt);
        const float scale = __expf(m_run - m_new);
        float p0[4], p1[4];
        float sum = 0.0f;
#pragma unroll
        for (int r = 0; r < 4; ++r) {
            p0[r] = __expf(s0[r] - m_new);
            p1[r] = __expf(s1[r] - m_new);
            sum += p0[r] + p1[r];
        }
        sum += __shfl_xor(sum, 16, 64);
        sum += __shfl_xor(sum, 32, 64);
        l_run = l_run * scale + sum;
        m_run = m_new;
#pragma unroll
        for (int i = 0; i < 4; ++i) o[i] *= scale;

        // P^T B-fragment: kappa(g,j) = 16*(j>>2) + 4g + (j&3) -- registers in place
        ushort8 bp;
#pragma unroll
        for (int r = 0; r < 4; ++r) { bp[r] = f2bf(p0[r]); bp[4 + r] = f2bf(p1[r]); }

        // V^T A-fragments with the SAME kappa: two contiguous 8B loads each
#pragma unroll
        for (int ht = 0; ht < 4; ++ht) {
            const unsigned short* vp = vb + (size_t)(16 * ht + l15) * TT + kv0 + 4 * g;
            ushort4v v0 = *(const ushort4v*)vp;         // keys 4g..4g+3
            ushort4v v1 = *(const ushort4v*)(vp + 16);  // keys 16+4g..16+4g+3
            ushort8 av;
#pragma unroll
            for (int r = 0; r < 4; ++r) { av[r] = v0[r]; av[4 + r] = v1[r]; }
            o[ht] = mfma16(av, bp, o[ht]);
        }
    }

    const float inv = 1.0f / l_run;  // >= 1 always (argmax key contributes 1)
    float* op = out + (size_t)(b * TT + q) * HH + 4 * g;
#pragma unroll
    for (int ht = 0; ht < 4; ++ht) {
        float4v r = o[ht] * inv;
        *(float4v*)(op + 16 * ht) = r;
    }
}

extern "C" void kernel_launch(void* const* d_in, const int* in_sizes, int n_in,
                              void* d_out, int out_size, void* d_ws, size_t ws_size,
                              hipStream_t stream) {
    // setup_inputs order: x, Wk, Wq, Wv
    const float* x  = (const float*)d_in[0];
    const float* Wk = (const float*)d_in[1];
    const float* Wq = (const float*)d_in[2];
    const float* Wv = (const float*)d_in[3];

    // workspace: q bf16 [B*T][64] | k bf16 [B*T][64] | vT bf16 [B][64][T]  (3 MiB)
    unsigned short* q_ws  = (unsigned short*)d_ws;
    unsigned short* k_ws  = q_ws + (size_t)BB * TT * HH;
    unsigned short* vt_ws = k_ws + (size_t)BB * TT * HH;

    dim3 g1(BB * TT / 64, 3);
    proj_kernel<<<g1, 256, 0, stream>>>(x, Wq, Wk, Wv, q_ws, k_ws, vt_ws);
    attn_kernel<<<BB * TT / 16, 64, 0, stream>>>(q_ws, k_ws, vt_ws, (float*)d_out);
}